// Round 9
// baseline (238.529 us; speedup 1.0000x reference)
//
#include <hip/hip_runtime.h>
#include <hip/hip_bf16.h>
#include <string.h>

#define B_ 32
#define LQ_ 256
#define H_ 256
#define NH_ 8
#define LK_ 512
#define N_ 8192
#define DH_ 32

typedef float floatx4 __attribute__((ext_vector_type(4)));
typedef short shortx8 __attribute__((ext_vector_type(8)));
typedef short shortx4 __attribute__((ext_vector_type(4)));

__device__ __forceinline__ short f2b(float f) {
    __hip_bfloat16 h = __float2bfloat16(f);
    short s;
    __builtin_memcpy(&s, &h, 2);
    return s;
}
__device__ __forceinline__ float b2f(short s) {
    unsigned u = ((unsigned)(unsigned short)s) << 16;
    float f;
    __builtin_memcpy(&f, &u, 4);
    return f;
}

#define LOG2E 1.44269504088896f
#define MFMA32(a, b, c) __builtin_amdgcn_mfma_f32_16x16x32_bf16(a, b, c, 0, 0, 0)
#define MFMA16(a, b, c) __builtin_amdgcn_mfma_f32_16x16x16bf16_1k(a, b, c, 0, 0, 0)
// async global->LDS, 16B/lane; LDS dest = wave-uniform base + lane*16 (m97)
typedef const __attribute__((address_space(1))) void* gptr_t;
typedef __attribute__((address_space(3))) void* lptr_t;
#define GLD16(g, l) __builtin_amdgcn_global_load_lds((gptr_t)(g), (lptr_t)(l), 16, 0, 0)

// ====== PHASE 1: head/row2e init ∥ prep_w ∥ gather ∥ query->bf16 =============
__global__ __launch_bounds__(256) void phase1(
    const float* __restrict__ graph, const float* __restrict__ rel,
    const int* __restrict__ src, const int* __restrict__ dst,
    const int* __restrict__ eb, const int* __restrict__ ep,
    const float* __restrict__ pad_mask, const float* __restrict__ query,
    const float* __restrict__ Wq, const float* __restrict__ Wk,
    const float* __restrict__ Wv, const float* __restrict__ Wo,
    const float* __restrict__ W1, const float* __restrict__ W2,
    short* __restrict__ WT, short* __restrict__ key_pad,
    short* __restrict__ val_pad, short* __restrict__ qbf,
    int* __restrict__ head, int* __restrict__ row2e, int E) {
    const int bid = blockIdx.x, tid = threadIdx.x;
    if (bid < 8192) {
        int row = bid * 2 + (tid >> 7);
        int t = tid & 127;
        int b = row >> 9, p = row & 511;
        bool valid = pad_mask[row] > 0.5f;
        size_t krow = (size_t)row * 512;
        size_t vrow = (size_t)row * 256;
        int kc = t * 4, vc = t * 2;
        if (valid) {
            int lo = 0, hi = E;
            while (lo < hi) { int mid = (lo + hi) >> 1; if (eb[mid] < b) lo = mid + 1; else hi = mid; }
            int e = lo + p;
            int s = src[e], d = dst[e];
            const float* sp = (kc < 256) ? (graph + (size_t)s * 256 + kc)
                                         : (rel + (size_t)e * 256 + (kc - 256));
            float4 k4 = *(const float4*)sp;
            key_pad[krow + kc + 0] = f2b(k4.x);
            key_pad[krow + kc + 1] = f2b(k4.y);
            key_pad[krow + kc + 2] = f2b(k4.z);
            key_pad[krow + kc + 3] = f2b(k4.w);
            float2 v2 = *(const float2*)(graph + (size_t)d * 256 + vc);
            val_pad[vrow + vc + 0] = f2b(v2.x);
            val_pad[vrow + vc + 1] = f2b(v2.y);
        } else {
            *(long long*)&key_pad[krow + kc] = 0;
            *(int*)&val_pad[vrow + vc] = 0;
        }
    } else if (bid < 9984) {
        int i = (bid - 8192) * 256 + tid;
        const float* s;
        int K, loc;
        if (i < 65536) { s = Wq; K = 256; loc = i; }
        else if (i < 196608) { s = Wk; K = 512; loc = i - 65536; }
        else {
            int m = (i - 196608) >> 16;
            loc = (i - 196608) & 65535;
            K = 256;
            s = (m == 0) ? Wv : (m == 1) ? Wo : (m == 2) ? W1 : W2;
        }
        int n = loc / K, k = loc - n * K;
        WT[i] = f2b(s[(size_t)k * 256 + n]);
    } else if (bid < 10016) {
        int i = (bid - 9984) * 256 + tid;   // 32 blocks -> 8192 threads
        if (i < 8192) head[i] = -1;
        for (int j = i; j < E; j += 8192)
            row2e[eb[j] * 512 + ep[j]] = j;
    } else {
        // query f32 -> bf16 (numerically identical to in-staging f2b)
        int i = (bid - 10016) * 256 + tid;   // 65536 threads x 32 elems
        const float* qp = query + (size_t)i * 32;
        short* op = qbf + (size_t)i * 32;
#pragma unroll
        for (int j = 0; j < 32; j += 4) {
            float4 v = *(const float4*)(qp + j);
            shortx4 o;
            o[0] = f2b(v.x); o[1] = f2b(v.y); o[2] = f2b(v.z); o[3] = f2b(v.w);
            *(long long*)(op + j) = *(long long*)&o;
        }
    }
}

// ===== PHASE 2: QKV GEMMs, 128x128 tiles, global_load_lds staging (m97-style) ==
__global__ __launch_bounds__(256) void phase2_gemm(
    const short* __restrict__ qbf, const short* __restrict__ key_pad,
    const short* __restrict__ val_pad, const short* __restrict__ WT,
    const float* __restrict__ bq, const float* __restrict__ bk,
    const float* __restrict__ bv,
    short* __restrict__ Qb, short* __restrict__ Kb,
    short* __restrict__ Vt, short* __restrict__ Qt) {
    __shared__ short As[128 * 32];   // unpadded (gload_lds requires linear dest)
    __shared__ short Bs[128 * 32];
    const int tid = threadIdx.x;
    const int id = blockIdx.x;
    const short* Ab; const short* Bb;
    const float* bias; short* C;
    size_t cbase; int cstride, K; bool biasM;
    if (id < 128) {
        int mt = id >> 1, nt = id & 1;
        Ab = qbf + (size_t)(mt * 128) * 256; K = 256;
        Bb = WT + (size_t)(nt * 128) * 256;
        bias = bq + nt * 128; biasM = false;
        C = Qb; cbase = (size_t)(mt * 128) * 256 + nt * 128; cstride = 256;
    } else if (id < 384) {
        int t = id - 128; int mt = t >> 1, nt = t & 1;
        Ab = key_pad + (size_t)(mt * 128) * 512; K = 512;
        Bb = WT + 65536 + (size_t)(nt * 128) * 512;
        bias = bk + nt * 128; biasM = false;
        C = Kb; cbase = (size_t)(mt * 128) * 256 + nt * 128; cstride = 256;
    } else if (id < 640) {
        int t = id - 384; int b = t >> 3, ct = (t >> 2) & 1, nt = t & 3;
        Ab = WT + 196608 + (size_t)(ct * 128) * 256; K = 256;
        Bb = val_pad + ((size_t)(b * 512 + nt * 128)) * 256;
        bias = bv + ct * 128; biasM = true;
        C = Vt; cbase = ((size_t)(b * 256 + ct * 128)) * 512 + nt * 128; cstride = 512;
    } else {
        int t = id - 640; int b = t >> 2, ct = (t >> 1) & 1, qt = t & 1;
        Ab = WT + (size_t)(ct * 128) * 256; K = 256;
        Bb = qbf + ((size_t)(b * 256 + qt * 128)) * 256;
        bias = bq + ct * 128; biasM = true;
        C = Qt; cbase = ((size_t)(b * 256 + ct * 128)) * 256 + qt * 128; cstride = 256;
    }
    const int w = tid >> 6, lane = tid & 63;
    const int R0 = (w >> 1) * 64, C0 = (w & 1) * 64;
    const int lm = lane & 15, quad = lane >> 4;
    const int srow = lane >> 2, scol = (lane & 3) * 8;   // 16 rows x 32 cols / wave-call

    floatx4 acc[4][4];
#pragma unroll
    for (int i = 0; i < 4; i++)
#pragma unroll
        for (int j = 0; j < 4; j++) acc[i][j] = {0.f, 0.f, 0.f, 0.f};

    for (int kc = 0; kc < K; kc += 32) {
#pragma unroll
        for (int c = 0; c < 2; c++) {
            const int row = w * 32 + c * 16;
            GLD16(Ab + (size_t)(row + srow) * K + kc + scol, &As[row * 32]);
            GLD16(Bb + (size_t)(row + srow) * K + kc + scol, &Bs[row * 32]);
        }
        __syncthreads();
        shortx8 af[4], bf[4];
#pragma unroll
        for (int i = 0; i < 4; i++) {
            af[i] = *(const shortx8*)&As[(R0 + i * 16 + lm) * 32 + quad * 8];
            bf[i] = *(const shortx8*)&Bs[(C0 + i * 16 + lm) * 32 + quad * 8];
        }
#pragma unroll
        for (int i = 0; i < 4; i++)
#pragma unroll
            for (int j = 0; j < 4; j++)
                acc[i][j] = MFMA32(af[i], bf[j], acc[i][j]);
        __syncthreads();
    }
#pragma unroll
    for (int i = 0; i < 4; i++) {
#pragma unroll
        for (int j = 0; j < 4; j++) {
            int gn = C0 + j * 16 + lm;
#pragma unroll
            for (int r = 0; r < 4; r++) {
                int gm = R0 + i * 16 + quad * 4 + r;
                float bvv = biasM ? bias[gm] : bias[gn];
                C[cbase + (size_t)gm * cstride + gn] = f2b(acc[i][j][r] + bvv);
            }
        }
    }
}

// ====== PHASE 3: attention, (b,h)-blocked; register-direct P via K=16 PV MFMA ==
__global__ __launch_bounds__(512, 4) void phase3_attn(
    const short* __restrict__ Qm, const short* __restrict__ Km,
    const short* __restrict__ Vt, const short* __restrict__ Qt,
    const float* __restrict__ pad_mask, const float* __restrict__ ext,
    short* __restrict__ qctx, short* __restrict__ vctx) {
    __shared__ short SA[128][40];    // K chunk [k][d] / Q chunk [q][d]
    __shared__ short ST[32][136];    // Vt slice [d][k] / Qt slice [d][q]
    const int tid = threadIdx.x;
    const int w = tid >> 6, lane = tid & 63;
    const int lm = lane & 15, quad = lane >> 4;
    const float scale2 = 0.17677669529663687f * LOG2E;
    const int id = blockIdx.x;

    if (id < 256) {
        const int b = id >> 3, h = id & 7;
        shortx8 bqf[2];
        bqf[0] = *(const shortx8*)(Qm + ((size_t)(b * 256 + w * 32 + lm)) * 256 + h * 32 + quad * 8);
        bqf[1] = *(const shortx8*)(Qm + ((size_t)(b * 256 + w * 32 + 16 + lm)) * 256 + h * 32 + quad * 8);
        floatx4 oacc[2][2] = {{{0.f,0.f,0.f,0.f},{0.f,0.f,0.f,0.f}},
                              {{0.f,0.f,0.f,0.f},{0.f,0.f,0.f,0.f}}};
        float psum[2] = {0.f, 0.f};
        const floatx4* pmp = (const floatx4*)(pad_mask + b * 512);
        for (int kc = 0; kc < 512; kc += 128) {
            if (tid < 256) {          // K chunk [128][32]
                int r = tid >> 1, dq = (tid & 1) * 16;
                const short* kp = Km + ((size_t)(b * 512 + kc + r)) * 256 + h * 32 + dq;
                *(shortx8*)&SA[r][dq] = *(const shortx8*)kp;
                *(shortx8*)&SA[r][dq + 8] = *(const shortx8*)(kp + 8);
            } else {                  // Vt slice [32][128]
                int u = tid - 256;
                int r = u >> 3, kq = (u & 7) * 16;
                const short* vp = Vt + ((size_t)(b * 256 + h * 32 + r)) * 512 + kc + kq;
                *(shortx8*)&ST[r][kq] = *(const shortx8*)vp;
                *(shortx8*)&ST[r][kq + 8] = *(const shortx8*)(vp + 8);
            }
            __syncthreads();
#pragma unroll
            for (int kh = 0; kh < 2; kh++) {
#pragma unroll
                for (int kt = 0; kt < 4; kt++) {
                    const int kw = kh * 64 + kt * 16;      // k window in chunk
                    shortx8 ak = *(const shortx8*)&SA[kw + lm][quad * 8];
                    floatx4 pm = pmp[kc / 4 + kh * 16 + kt * 4 + quad];
                    shortx4 av0 = *(const shortx4*)&ST[lm][kw + quad * 4];
                    shortx4 av1 = *(const shortx4*)&ST[16 + lm][kw + quad * 4];
#pragma unroll
                    for (int qf = 0; qf < 2; qf++) {
                        floatx4 s = {0.f, 0.f, 0.f, 0.f};
                        s = MFMA32(ak, bqf[qf], s);
                        shortx4 p4;
#pragma unroll
                        for (int r = 0; r < 4; r++) {
                            float e = __builtin_amdgcn_exp2f(
                                s[r] * scale2 + (1.0f - pm[r]) * (-10000.0f * LOG2E));
                            psum[qf] += e;
                            p4[r] = f2b(e);
                        }
                        oacc[qf][0] = MFMA16(av0, p4, oacc[qf][0]);
                        oacc[qf][1] = MFMA16(av1, p4, oacc[qf][1]);
                    }
                }
            }
            __syncthreads();
        }
#pragma unroll
        for (int qf = 0; qf < 2; qf++) {
            psum[qf] += __shfl_xor(psum[qf], 16, 64);
            psum[qf] += __shfl_xor(psum[qf], 32, 64);
            float inv = 1.0f / psum[qf];
            int q = w * 32 + qf * 16 + lm;
            short* op = qctx + ((size_t)(b * 256 + q)) * 256 + h * 32;
#pragma unroll
            for (int di = 0; di < 2; di++) {
                shortx4 o;
#pragma unroll
                for (int r = 0; r < 4; r++) o[r] = f2b(oacc[qf][di][r] * inv);
                *(long long*)(op + di * 16 + quad * 4) = *(long long*)&o;
            }
        }
    } else {
        const int t = id - 256;
        const int b = t >> 4, h = (t >> 1) & 7, khb = t & 1;
        shortx8 bkf[2];
        bkf[0] = *(const shortx8*)(Km + ((size_t)(b * 512 + khb * 256 + w * 32 + lm)) * 256 + h * 32 + quad * 8);
        bkf[1] = *(const shortx8*)(Km + ((size_t)(b * 512 + khb * 256 + w * 32 + 16 + lm)) * 256 + h * 32 + quad * 8);
        floatx4 oacc[2][2] = {{{0.f,0.f,0.f,0.f},{0.f,0.f,0.f,0.f}},
                              {{0.f,0.f,0.f,0.f},{0.f,0.f,0.f,0.f}}};
        float psum[2] = {0.f, 0.f};
        const floatx4* emp = (const floatx4*)(ext + b * 256);
        for (int qc = 0; qc < 256; qc += 128) {
            if (tid < 256) {          // Q chunk [128][32]
                int r = tid >> 1, dq = (tid & 1) * 16;
                const short* qp = Qm + ((size_t)(b * 256 + qc + r)) * 256 + h * 32 + dq;
                *(shortx8*)&SA[r][dq] = *(const shortx8*)qp;
                *(shortx8*)&SA[r][dq + 8] = *(const shortx8*)(qp + 8);
            } else {                  // Qt slice [32][128]
                int u = tid - 256;
                int r = u >> 3, kq = (u & 7) * 16;
                const short* tp = Qt + ((size_t)(b * 256 + h * 32 + r)) * 256 + qc + kq;
                *(shortx8*)&ST[r][kq] = *(const shortx8*)tp;
                *(shortx8*)&ST[r][kq + 8] = *(const shortx8*)(tp + 8);
            }
            __syncthreads();
#pragma unroll
            for (int qh = 0; qh < 2; qh++) {
#pragma unroll
                for (int qt = 0; qt < 4; qt++) {
                    const int qw = qh * 64 + qt * 16;      // q window in chunk
                    shortx8 aq = *(const shortx8*)&SA[qw + lm][quad * 8];
                    floatx4 em = emp[qc / 4 + qh * 16 + qt * 4 + quad];
                    shortx4 av0 = *(const shortx4*)&ST[lm][qw + quad * 4];
                    shortx4 av1 = *(const shortx4*)&ST[16 + lm][qw + quad * 4];
#pragma unroll
                    for (int kf = 0; kf < 2; kf++) {
                        floatx4 s = {0.f, 0.f, 0.f, 0.f};
                        s = MFMA32(aq, bkf[kf], s);
                        shortx4 p4;
#pragma unroll
                        for (int r = 0; r < 4; r++) {
                            float e = __builtin_amdgcn_exp2f(s[r] * scale2 + em[r] * LOG2E);
                            psum[kf] += e;
                            p4[r] = f2b(e);
                        }
                        oacc[kf][0] = MFMA16(av0, p4, oacc[kf][0]);
                        oacc[kf][1] = MFMA16(av1, p4, oacc[kf][1]);
                    }
                }
            }
            __syncthreads();
        }
#pragma unroll
        for (int kf = 0; kf < 2; kf++) {
            psum[kf] += __shfl_xor(psum[kf], 16, 64);
            psum[kf] += __shfl_xor(psum[kf], 32, 64);
            float inv = 1.0f / psum[kf];
            int k = khb * 256 + w * 32 + kf * 16 + lm;
            short* op = vctx + ((size_t)(b * 512 + k)) * 256 + h * 32;
#pragma unroll
            for (int di = 0; di < 2; di++) {
                shortx4 o;
#pragma unroll
                for (int r = 0; r < 4; r++) o[r] = f2b(oacc[kf][di][r] * inv);
                *(long long*)(op + di * 16 + quad * 4) = *(long long*)&o;
            }
        }
    }
}

// == PHASE 4a: tail GEMMs, 128x128 tiles, f32 out, global_load_lds staging =====
__global__ __launch_bounds__(256) void phase4a_gemm(
    const short* __restrict__ qctx, const short* __restrict__ vctx,
    const short* __restrict__ val_pad, const short* __restrict__ WTo,
    const short* __restrict__ WT1, const short* __restrict__ WT2,
    float* __restrict__ obuf, float* __restrict__ tbuf) {
    __shared__ short As[128 * 32];
    __shared__ short Bs[128 * 32];
    const int tid = threadIdx.x;
    const int id = blockIdx.x;
    const bool is_out = id < 128;
    int t = is_out ? id : id - 128;
    const int mt = t >> 1, nt = t & 1;
    const int w = tid >> 6, lane = tid & 63;
    const int R0 = (w >> 1) * 64, C0 = (w & 1) * 64;
    const int lm = lane & 15, quad = lane >> 4;
    const int srow = lane >> 2, scol = (lane & 3) * 8;
    const int npair = is_out ? 1 : 2;

    floatx4 acc[4][4];
#pragma unroll
    for (int i = 0; i < 4; i++)
#pragma unroll
        for (int j = 0; j < 4; j++) acc[i][j] = {0.f, 0.f, 0.f, 0.f};

    for (int pair = 0; pair < npair; pair++) {
        const short* Ap = is_out ? (qctx + (size_t)(mt * 128) * 256)
                                 : (pair == 0 ? vctx + (size_t)(mt * 128) * 256
                                              : val_pad + (size_t)(mt * 128) * 256);
        const short* Bp = is_out ? (WTo + (size_t)(nt * 128) * 256)
                                 : (pair == 0 ? WT1 + (size_t)(nt * 128) * 256
                                              : WT2 + (size_t)(nt * 128) * 256);
        for (int kc = 0; kc < 256; kc += 32) {
#pragma unroll
            for (int c = 0; c < 2; c++) {
                const int row = w * 32 + c * 16;
                GLD16(Ap + (size_t)(row + srow) * 256 + kc + scol, &As[row * 32]);
                GLD16(Bp + (size_t)(row + srow) * 256 + kc + scol, &Bs[row * 32]);
            }
            __syncthreads();
            shortx8 af[4], bf[4];
#pragma unroll
            for (int i = 0; i < 4; i++) {
                af[i] = *(const shortx8*)&As[(R0 + i * 16 + lm) * 32 + quad * 8];
                bf[i] = *(const shortx8*)&Bs[(C0 + i * 16 + lm) * 32 + quad * 8];
            }
#pragma unroll
            for (int i = 0; i < 4; i++)
#pragma unroll
                for (int j = 0; j < 4; j++)
                    acc[i][j] = MFMA32(af[i], bf[j], acc[i][j]);
            __syncthreads();
        }
    }
    float* C = is_out ? obuf : tbuf;
    const size_t cbase = (size_t)(mt * 128) * 256 + nt * 128;
#pragma unroll
    for (int i = 0; i < 4; i++) {
#pragma unroll
        for (int j = 0; j < 4; j++) {
            int gn = C0 + j * 16 + lm;
#pragma unroll
            for (int r = 0; r < 4; r++) {
                int gm = R0 + i * 16 + quad * 4 + r;
                C[cbase + (size_t)gm * 256 + gn] = acc[i][j][r];
            }
        }
    }
}

// ===== PHASE 4b: LN epilogues (1 row / wave); gate writes y in-place into tbuf
//       and pushes its row onto a per-dst lock-free list (1 atomicExch / row) ====
__global__ __launch_bounds__(256) void phase4b_ln(
    const float* __restrict__ obuf, const float* __restrict__ bo,
    const float* __restrict__ query, const float* __restrict__ g1,
    const float* __restrict__ be1, float* __restrict__ out_q,
    float* __restrict__ tbuf, const short* __restrict__ vctx,
    const short* __restrict__ val_pad, const float* __restrict__ b1_,
    const float* __restrict__ b2_, const float* __restrict__ g2,
    const float* __restrict__ be2, const float* __restrict__ pad_mask,
    const int* __restrict__ row2e, const int* __restrict__ dst,
    int* __restrict__ head, int* __restrict__ nxt) {
    const int lane = threadIdx.x & 63, w = threadIdx.x >> 6;
    const int c0 = lane * 4;
    if (blockIdx.x < 2048) {
        int row = blockIdx.x * 4 + w;
        long long base = (long long)row * H_ + c0;
        float4 o = *(const float4*)(obuf + base);
        float4 bo4 = *(const float4*)(bo + c0);
        float4 q4 = *(const float4*)(query + base);
        float x0 = o.x + bo4.x + q4.x, x1 = o.y + bo4.y + q4.y;
        float x2 = o.z + bo4.z + q4.z, x3 = o.w + bo4.w + q4.w;
        float t = x0 + x1 + x2 + x3;
        for (int off = 32; off > 0; off >>= 1) t += __shfl_xor(t, off, 64);
        float mean = t * (1.0f / H_);
        float d0 = x0 - mean, d1 = x1 - mean, d2 = x2 - mean, d3 = x3 - mean;
        float v = d0 * d0 + d1 * d1 + d2 * d2 + d3 * d3;
        for (int off = 32; off > 0; off >>= 1) v += __shfl_xor(v, off, 64);
        float rs = rsqrtf(v * (1.0f / H_) + 1e-12f);
        float4 g = *(const float4*)(g1 + c0);
        float4 be = *(const float4*)(be1 + c0);
        float4 out;
        out.x = d0 * rs * g.x + be.x; out.y = d1 * rs * g.y + be.y;
        out.z = d2 * rs * g.z + be.z; out.w = d3 * rs * g.w + be.w;
        *(float4*)(out_q + base) = out;
    } else {
        int row = (blockIdx.x - 2048) * 4 + w;
        if (pad_mask[row] > 0.5f) {
            long long base = (long long)row * H_ + c0;
            float4 tb = *(const float4*)(tbuf + base);
            float4 b14 = *(const float4*)(b1_ + c0);
            float4 b24 = *(const float4*)(b2_ + c0);
            shortx4 vc = *(const shortx4*)(vctx + base);
            shortx4 vp = *(const shortx4*)(val_pad + base);
            float x[4];
#pragma unroll
            for (int j = 0; j < 4; j++) {
                float tv = (j == 0) ? tb.x : (j == 1) ? tb.y : (j == 2) ? tb.z : tb.w;
                float bb1 = (j == 0) ? b14.x : (j == 1) ? b14.y : (j == 2) ? b14.z : b14.w;
                float bb2 = (j == 0) ? b24.x : (j == 1) ? b24.y : (j == 2) ? b24.z : b24.w;
                float th = 1.0f / (1.0f + __expf(-(tv + bb1 + bb2)));
                x[j] = th * b2f(vc[j]) + (1.0f - th) * b2f(vp[j]);
            }
            float t = x[0] + x[1] + x[2] + x[3];
            for (int off = 32; off > 0; off >>= 1) t += __shfl_xor(t, off, 64);
            float mean = t * (1.0f / H_);
            float d0 = x[0] - mean, d1 = x[1] - mean, d2 = x[2] - mean, d3 = x[3] - mean;
            float v = d0 * d0 + d1 * d1 + d2 * d2 + d3 * d3;
            for (int off = 32; off > 0; off >>= 1) v += __shfl_xor(v, off, 64);
            float rs = rsqrtf(v * (1.0f / H_) + 1e-12f);
            float4 g = *(const float4*)(g2 + c0);
            float4 be = *(const float4*)(be2 + c0);
            float4 y4;
            y4.x = d0 * rs * g.x + be.x; y4.y = d1 * rs * g.y + be.y;
            y4.z = d2 * rs * g.z + be.z; y4.w = d3 * rs * g.w + be.w;
            *(float4*)(tbuf + base) = y4;   // in-place: same addresses just read
            if (lane == 0) {
                int d = dst[row2e[row]];
                int prev = atomicExch(&head[d], row);
                nxt[row] = prev;
            }
        }
    }
}

// ================= PHASE 5: finalize (walk per-node edge list) =================
__global__ __launch_bounds__(256) void finalize_graph(
    const int* __restrict__ head, const int* __restrict__ nxt,
    const float* __restrict__ yrows, const float* __restrict__ graph,
    float* __restrict__ out_g) {
    int n = blockIdx.x, c = threadIdx.x;
    long long idx = (long long)n * H_ + c;
    int e = head[n];
    if (e < 0) { out_g[idx] = graph[idx]; return; }
    float acc = 0.f;
    int cnt = 0;
    while (e >= 0) {
        acc += yrows[(size_t)e * H_ + c];
        cnt++;
        e = nxt[e];
    }
    out_g[idx] = acc / (float)cnt;
}

extern "C" void kernel_launch(void* const* d_in, const int* in_sizes, int n_in,
                              void* d_out, int out_size, void* d_ws, size_t ws_size,
                              hipStream_t stream) {
    const float* ext_mask = (const float*)d_in[0];
    const float* query    = (const float*)d_in[1];
    const float* rel      = (const float*)d_in[2];
    const float* graph    = (const float*)d_in[3];
    const int*  src      = (const int*)d_in[4];
    const int*  dst      = (const int*)d_in[5];
    const int*  eb       = (const int*)d_in[6];
    const int*  ep       = (const int*)d_in[7];
    const float* pad_mask = (const float*)d_in[8];
    const float* Wq = (const float*)d_in[9];  const float* bq = (const float*)d_in[10];
    const float* Wk = (const float*)d_in[11]; const float* bk = (const float*)d_in[12];
    const float* Wv = (const float*)d_in[13]; const float* bv = (const float*)d_in[14];
    const float* Wo = (const float*)d_in[15]; const float* bo = (const float*)d_in[16];
    const float* g1 = (const float*)d_in[17]; const float* be1 = (const float*)d_in[18];
    const float* W1 = (const float*)d_in[19]; const float* b1 = (const float*)d_in[20];
    const float* W2 = (const float*)d_in[21]; const float* b2 = (const float*)d_in[22];
    const float* g2 = (const float*)d_in[23]; const float* be2 = (const float*)d_in[24];
    const int E = in_sizes[2] / H_;

    float* out_g = (float*)d_out;
    float* out_q = (float*)d_out + (size_t)N_ * H_;

    short* sp = (short*)d_ws;
    short* key_pad = sp; sp += (size_t)B_ * LK_ * 2 * H_;
    short* val_pad = sp; sp += (size_t)B_ * LK_ * H_;
    short* Qb      = sp; sp += (size_t)B_ * LQ_ * H_;
    short* Kb      = sp; sp += (size_t)B_ * LK_ * H_;
    short* Vt      = sp; sp += (size_t)B_ * H_ * LK_;   // [b][c][k]
    short* Qt      = sp; sp += (size_t)B_ * H_ * LQ_;   // [b][c][q]
    short* qctx    = sp; sp += (size_t)B_ * LQ_ * H_;
    short* vctx    = sp; sp += (size_t)B_ * LK_ * H_;
    short* qbf     = sp; sp += (size_t)B_ * LQ_ * H_;   // query in bf16
    short* WT      = sp; sp += 458752;
    short* WTo = WT + 262144;
    short* WT1 = WT + 327680;
    short* WT2 = WT + 393216;
    int* ip = (int*)(((size_t)sp + 15) & ~(size_t)15);
    int* head  = ip; ip += N_;          // 8192
    int* nxt   = ip; ip += B_ * LK_;    // 16384
    int* row2e = ip; ip += B_ * LK_;    // 16384
    float* fp = (float*)ip;
    float* obuf = fp; fp += (size_t)B_ * LQ_ * H_;   // f32 [8192,256]
    float* tbuf = fp; fp += (size_t)B_ * LK_ * H_;   // f32 [16384,256]

    phase1<<<10272, 256, 0, stream>>>(graph, rel, src, dst, eb, ep, pad_mask,
                                      query, Wq, Wk, Wv, Wo, W1, W2,
                                      WT, key_pad, val_pad, qbf, head, row2e, E);
    phase2_gemm<<<768, 256, 0, stream>>>(qbf, key_pad, val_pad, WT,
                                         bq, bk, bv, Qb, Kb, Vt, Qt);
    phase3_attn<<<768, 512, 0, stream>>>(Qb, Kb, Vt, Qt, pad_mask, ext_mask,
                                         qctx, vctx);
    phase4a_gemm<<<384, 256, 0, stream>>>(qctx, vctx, val_pad, WTo, WT1, WT2,
                                          obuf, tbuf);
    phase4b_ln<<<6144, 256, 0, stream>>>(obuf, bo, query, g1, be1, out_q,
                                         tbuf, vctx, val_pad, b1, b2, g2, be2,
                                         pad_mask, row2e, dst, head, nxt);
    finalize_graph<<<N_, 256, 0, stream>>>(head, nxt, tbuf, graph, out_g);
}

// Round 10
// 230.864 us; speedup vs baseline: 1.0332x; 1.0332x over previous
//
#include <hip/hip_runtime.h>
#include <hip/hip_bf16.h>
#include <string.h>

#define B_ 32
#define LQ_ 256
#define H_ 256
#define NH_ 8
#define LK_ 512
#define N_ 8192
#define DH_ 32

typedef float floatx4 __attribute__((ext_vector_type(4)));
typedef short shortx8 __attribute__((ext_vector_type(8)));
typedef short shortx4 __attribute__((ext_vector_type(4)));

__device__ __forceinline__ short f2b(float f) {
    __hip_bfloat16 h = __float2bfloat16(f);
    short s;
    __builtin_memcpy(&s, &h, 2);
    return s;
}
__device__ __forceinline__ float b2f(short s) {
    unsigned u = ((unsigned)(unsigned short)s) << 16;
    float f;
    __builtin_memcpy(&f, &u, 4);
    return f;
}

#define LOG2E 1.44269504088896f
#define MFMA32(a, b, c) __builtin_amdgcn_mfma_f32_16x16x32_bf16(a, b, c, 0, 0, 0)
#define MFMA16(a, b, c) __builtin_amdgcn_mfma_f32_16x16x16bf16_1k(a, b, c, 0, 0, 0)
// async global->LDS, 16B/lane; LDS dest = wave-uniform base + lane*16 (m97)
typedef const __attribute__((address_space(1))) void* gptr_t;
typedef __attribute__((address_space(3))) void* lptr_t;
#define GLD16(g, l) __builtin_amdgcn_global_load_lds((gptr_t)(g), (lptr_t)(l), 16, 0, 0)

// ====== PHASE 0: per-batch edge-base lower bounds (kills gather's dep chain) ===
__global__ __launch_bounds__(64) void phase0(
    const int* __restrict__ eb, int* __restrict__ ebase, int E) {
    int b = threadIdx.x;
    if (b < 32) {
        int lo = 0, hi = E;
        while (lo < hi) { int mid = (lo + hi) >> 1; if (eb[mid] < b) lo = mid + 1; else hi = mid; }
        ebase[b] = lo;
    }
}

// == PHASE 1: gather ∥ tiled-W-transpose ∥ head/row2e ∥ query->bf16 ============
__global__ __launch_bounds__(256) void phase1(
    const float* __restrict__ graph, const float* __restrict__ rel,
    const int* __restrict__ src, const int* __restrict__ dst,
    const int* __restrict__ eb, const int* __restrict__ ep,
    const float* __restrict__ pad_mask, const float* __restrict__ query,
    const float* __restrict__ Wq, const float* __restrict__ Wk,
    const float* __restrict__ Wv, const float* __restrict__ Wo,
    const float* __restrict__ W1, const float* __restrict__ W2,
    short* __restrict__ WT, short* __restrict__ key_pad,
    short* __restrict__ val_pad, short* __restrict__ qbf,
    int* __restrict__ head, int* __restrict__ row2e,
    const int* __restrict__ ebase, int E) {
    __shared__ short SL[64][72];
    const int bid = blockIdx.x, tid = threadIdx.x;
    if (bid < 8192) {
        int row = bid * 2 + (tid >> 7);
        int t = tid & 127;
        int b = row >> 9, p = row & 511;
        bool valid = pad_mask[row] > 0.5f;
        size_t krow = (size_t)row * 512;
        size_t vrow = (size_t)row * 256;
        int kc = t * 4, vc = t * 2;
        if (valid) {
            int e = ebase[b] + p;
            int s = src[e], d = dst[e];
            const float* sp = (kc < 256) ? (graph + (size_t)s * 256 + kc)
                                         : (rel + (size_t)e * 256 + (kc - 256));
            float4 k4 = *(const float4*)sp;
            key_pad[krow + kc + 0] = f2b(k4.x);
            key_pad[krow + kc + 1] = f2b(k4.y);
            key_pad[krow + kc + 2] = f2b(k4.z);
            key_pad[krow + kc + 3] = f2b(k4.w);
            float2 v2 = *(const float2*)(graph + (size_t)d * 256 + vc);
            val_pad[vrow + vc + 0] = f2b(v2.x);
            val_pad[vrow + vc + 1] = f2b(v2.y);
        } else {
            *(long long*)&key_pad[krow + kc] = 0;
            *(int*)&val_pad[vrow + vc] = 0;
        }
    } else if (bid < 8304) {
        // 112 x 64x64 LDS-tiled transposes: WT[woff + n*K + k] = bf16(s[k*256+n])
        int t = bid - 8192;
        const float* s; int K, woff, tt;
        if (t < 16) { s = Wq; K = 256; woff = 0; tt = t; }
        else if (t < 48) { s = Wk; K = 512; woff = 65536; tt = t - 16; }
        else {
            int m = (t - 48) >> 4; tt = (t - 48) & 15; K = 256;
            s = (m == 0) ? Wv : (m == 1) ? Wo : (m == 2) ? W1 : W2;
            woff = 196608 + m * 65536;
        }
        int k0 = (tt >> 2) * 64, n0 = (tt & 3) * 64;
        int rr = tid >> 2, cc = (tid & 3) * 16;
        const float* sp = s + (size_t)(k0 + rr) * 256 + n0 + cc;
#pragma unroll
        for (int j = 0; j < 16; j += 4) {
            float4 v = *(const float4*)(sp + j);
            SL[rr][cc + j + 0] = f2b(v.x); SL[rr][cc + j + 1] = f2b(v.y);
            SL[rr][cc + j + 2] = f2b(v.z); SL[rr][cc + j + 3] = f2b(v.w);
        }
        __syncthreads();
        int nn = tid >> 2, kk = (tid & 3) * 16;
        shortx8 o0, o1;
#pragma unroll
        for (int j = 0; j < 8; j++) { o0[j] = SL[kk + j][nn]; o1[j] = SL[kk + 8 + j][nn]; }
        short* wp = WT + (size_t)woff + (size_t)(n0 + nn) * K + k0 + kk;
        *(shortx8*)wp = o0;
        *(shortx8*)(wp + 8) = o1;
    } else if (bid < 8336) {
        int i = (bid - 8304) * 256 + tid;   // 32 blocks -> 8192 threads
        if (i < 8192) head[i] = -1;
        for (int j = i; j < E; j += 8192)
            row2e[eb[j] * 512 + ep[j]] = j;
    } else {
        // query f32 -> bf16 (numerically identical to in-staging f2b)
        int i = (bid - 8336) * 256 + tid;   // 65536 threads x 32 elems
        const float* qp = query + (size_t)i * 32;
        short* op = qbf + (size_t)i * 32;
#pragma unroll
        for (int j = 0; j < 32; j += 4) {
            float4 v = *(const float4*)(qp + j);
            shortx4 o;
            o[0] = f2b(v.x); o[1] = f2b(v.y); o[2] = f2b(v.z); o[3] = f2b(v.w);
            *(long long*)(op + j) = *(long long*)&o;
        }
    }
}

// ===== PHASE 2: QKV GEMMs, 128x128 tiles, global_load_lds staging (m97-style) ==
__global__ __launch_bounds__(256) void phase2_gemm(
    const short* __restrict__ qbf, const short* __restrict__ key_pad,
    const short* __restrict__ val_pad, const short* __restrict__ WT,
    const float* __restrict__ bq, const float* __restrict__ bk,
    const float* __restrict__ bv,
    short* __restrict__ Qb, short* __restrict__ Kb,
    short* __restrict__ Vt, short* __restrict__ Qt) {
    __shared__ short As[128 * 32];   // unpadded (gload_lds requires linear dest)
    __shared__ short Bs[128 * 32];
    const int tid = threadIdx.x;
    const int id = blockIdx.x;
    const short* Ab; const short* Bb;
    const float* bias; short* C;
    size_t cbase; int cstride, K; bool biasM;
    if (id < 128) {
        int mt = id >> 1, nt = id & 1;
        Ab = qbf + (size_t)(mt * 128) * 256; K = 256;
        Bb = WT + (size_t)(nt * 128) * 256;
        bias = bq + nt * 128; biasM = false;
        C = Qb; cbase = (size_t)(mt * 128) * 256 + nt * 128; cstride = 256;
    } else if (id < 384) {
        int t = id - 128; int mt = t >> 1, nt = t & 1;
        Ab = key_pad + (size_t)(mt * 128) * 512; K = 512;
        Bb = WT + 65536 + (size_t)(nt * 128) * 512;
        bias = bk + nt * 128; biasM = false;
        C = Kb; cbase = (size_t)(mt * 128) * 256 + nt * 128; cstride = 256;
    } else if (id < 640) {
        int t = id - 384; int b = t >> 3, ct = (t >> 2) & 1, nt = t & 3;
        Ab = WT + 196608 + (size_t)(ct * 128) * 256; K = 256;
        Bb = val_pad + ((size_t)(b * 512 + nt * 128)) * 256;
        bias = bv + ct * 128; biasM = true;
        C = Vt; cbase = ((size_t)(b * 256 + ct * 128)) * 512 + nt * 128; cstride = 512;
    } else {
        int t = id - 640; int b = t >> 2, ct = (t >> 1) & 1, qt = t & 1;
        Ab = WT + (size_t)(ct * 128) * 256; K = 256;
        Bb = qbf + ((size_t)(b * 256 + qt * 128)) * 256;
        bias = bq + ct * 128; biasM = true;
        C = Qt; cbase = ((size_t)(b * 256 + ct * 128)) * 256 + qt * 128; cstride = 256;
    }
    const int w = tid >> 6, lane = tid & 63;
    const int R0 = (w >> 1) * 64, C0 = (w & 1) * 64;
    const int lm = lane & 15, quad = lane >> 4;
    const int srow = lane >> 2, scol = (lane & 3) * 8;   // 16 rows x 32 cols / wave-call

    floatx4 acc[4][4];
#pragma unroll
    for (int i = 0; i < 4; i++)
#pragma unroll
        for (int j = 0; j < 4; j++) acc[i][j] = {0.f, 0.f, 0.f, 0.f};

    for (int kc = 0; kc < K; kc += 32) {
#pragma unroll
        for (int c = 0; c < 2; c++) {
            const int row = w * 32 + c * 16;
            GLD16(Ab + (size_t)(row + srow) * K + kc + scol, &As[row * 32]);
            GLD16(Bb + (size_t)(row + srow) * K + kc + scol, &Bs[row * 32]);
        }
        __syncthreads();
        shortx8 af[4], bf[4];
#pragma unroll
        for (int i = 0; i < 4; i++) {
            af[i] = *(const shortx8*)&As[(R0 + i * 16 + lm) * 32 + quad * 8];
            bf[i] = *(const shortx8*)&Bs[(C0 + i * 16 + lm) * 32 + quad * 8];
        }
#pragma unroll
        for (int i = 0; i < 4; i++)
#pragma unroll
            for (int j = 0; j < 4; j++)
                acc[i][j] = MFMA32(af[i], bf[j], acc[i][j]);
        __syncthreads();
    }
#pragma unroll
    for (int i = 0; i < 4; i++) {
#pragma unroll
        for (int j = 0; j < 4; j++) {
            int gn = C0 + j * 16 + lm;
#pragma unroll
            for (int r = 0; r < 4; r++) {
                int gm = R0 + i * 16 + quad * 4 + r;
                float bvv = biasM ? bias[gm] : bias[gn];
                C[cbase + (size_t)gm * cstride + gn] = f2b(acc[i][j][r] + bvv);
            }
        }
    }
}

// ====== PHASE 3: attention, (b,h)-blocked; register-direct P via K=16 PV MFMA ==
__global__ __launch_bounds__(512, 4) void phase3_attn(
    const short* __restrict__ Qm, const short* __restrict__ Km,
    const short* __restrict__ Vt, const short* __restrict__ Qt,
    const float* __restrict__ pad_mask, const float* __restrict__ ext,
    short* __restrict__ qctx, short* __restrict__ vctx) {
    __shared__ short SA[128][40];    // K chunk [k][d] / Q chunk [q][d]
    __shared__ short ST[32][136];    // Vt slice [d][k] / Qt slice [d][q]
    const int tid = threadIdx.x;
    const int w = tid >> 6, lane = tid & 63;
    const int lm = lane & 15, quad = lane >> 4;
    const float scale2 = 0.17677669529663687f * LOG2E;
    const int id = blockIdx.x;

    if (id < 256) {
        const int b = id >> 3, h = id & 7;
        shortx8 bqf[2];
        bqf[0] = *(const shortx8*)(Qm + ((size_t)(b * 256 + w * 32 + lm)) * 256 + h * 32 + quad * 8);
        bqf[1] = *(const shortx8*)(Qm + ((size_t)(b * 256 + w * 32 + 16 + lm)) * 256 + h * 32 + quad * 8);
        floatx4 oacc[2][2] = {{{0.f,0.f,0.f,0.f},{0.f,0.f,0.f,0.f}},
                              {{0.f,0.f,0.f,0.f},{0.f,0.f,0.f,0.f}}};
        float psum[2] = {0.f, 0.f};
        const floatx4* pmp = (const floatx4*)(pad_mask + b * 512);
        for (int kc = 0; kc < 512; kc += 128) {
            if (tid < 256) {          // K chunk [128][32]
                int r = tid >> 1, dq = (tid & 1) * 16;
                const short* kp = Km + ((size_t)(b * 512 + kc + r)) * 256 + h * 32 + dq;
                *(shortx8*)&SA[r][dq] = *(const shortx8*)kp;
                *(shortx8*)&SA[r][dq + 8] = *(const shortx8*)(kp + 8);
            } else {                  // Vt slice [32][128]
                int u = tid - 256;
                int r = u >> 3, kq = (u & 7) * 16;
                const short* vp = Vt + ((size_t)(b * 256 + h * 32 + r)) * 512 + kc + kq;
                *(shortx8*)&ST[r][kq] = *(const shortx8*)vp;
                *(shortx8*)&ST[r][kq + 8] = *(const shortx8*)(vp + 8);
            }
            __syncthreads();
#pragma unroll
            for (int kh = 0; kh < 2; kh++) {
#pragma unroll
                for (int kt = 0; kt < 4; kt++) {
                    const int kw = kh * 64 + kt * 16;      // k window in chunk
                    shortx8 ak = *(const shortx8*)&SA[kw + lm][quad * 8];
                    floatx4 pm = pmp[kc / 4 + kh * 16 + kt * 4 + quad];
                    shortx4 av0 = *(const shortx4*)&ST[lm][kw + quad * 4];
                    shortx4 av1 = *(const shortx4*)&ST[16 + lm][kw + quad * 4];
#pragma unroll
                    for (int qf = 0; qf < 2; qf++) {
                        floatx4 s = {0.f, 0.f, 0.f, 0.f};
                        s = MFMA32(ak, bqf[qf], s);
                        shortx4 p4;
#pragma unroll
                        for (int r = 0; r < 4; r++) {
                            float e = __builtin_amdgcn_exp2f(
                                s[r] * scale2 + (1.0f - pm[r]) * (-10000.0f * LOG2E));
                            psum[qf] += e;
                            p4[r] = f2b(e);
                        }
                        oacc[qf][0] = MFMA16(av0, p4, oacc[qf][0]);
                        oacc[qf][1] = MFMA16(av1, p4, oacc[qf][1]);
                    }
                }
            }
            __syncthreads();
        }
#pragma unroll
        for (int qf = 0; qf < 2; qf++) {
            psum[qf] += __shfl_xor(psum[qf], 16, 64);
            psum[qf] += __shfl_xor(psum[qf], 32, 64);
            float inv = 1.0f / psum[qf];
            int q = w * 32 + qf * 16 + lm;
            short* op = qctx + ((size_t)(b * 256 + q)) * 256 + h * 32;
#pragma unroll
            for (int di = 0; di < 2; di++) {
                shortx4 o;
#pragma unroll
                for (int r = 0; r < 4; r++) o[r] = f2b(oacc[qf][di][r] * inv);
                *(long long*)(op + di * 16 + quad * 4) = *(long long*)&o;
            }
        }
    } else {
        const int t = id - 256;
        const int b = t >> 4, h = (t >> 1) & 7, khb = t & 1;
        shortx8 bkf[2];
        bkf[0] = *(const shortx8*)(Km + ((size_t)(b * 512 + khb * 256 + w * 32 + lm)) * 256 + h * 32 + quad * 8);
        bkf[1] = *(const shortx8*)(Km + ((size_t)(b * 512 + khb * 256 + w * 32 + 16 + lm)) * 256 + h * 32 + quad * 8);
        floatx4 oacc[2][2] = {{{0.f,0.f,0.f,0.f},{0.f,0.f,0.f,0.f}},
                              {{0.f,0.f,0.f,0.f},{0.f,0.f,0.f,0.f}}};
        float psum[2] = {0.f, 0.f};
        const floatx4* emp = (const floatx4*)(ext + b * 256);
        for (int qc = 0; qc < 256; qc += 128) {
            if (tid < 256) {          // Q chunk [128][32]
                int r = tid >> 1, dq = (tid & 1) * 16;
                const short* qp = Qm + ((size_t)(b * 256 + qc + r)) * 256 + h * 32 + dq;
                *(shortx8*)&SA[r][dq] = *(const shortx8*)qp;
                *(shortx8*)&SA[r][dq + 8] = *(const shortx8*)(qp + 8);
            } else {                  // Qt slice [32][128]
                int u = tid - 256;
                int r = u >> 3, kq = (u & 7) * 16;
                const short* tp = Qt + ((size_t)(b * 256 + h * 32 + r)) * 256 + qc + kq;
                *(shortx8*)&ST[r][kq] = *(const shortx8*)tp;
                *(shortx8*)&ST[r][kq + 8] = *(const shortx8*)(tp + 8);
            }
            __syncthreads();
#pragma unroll
            for (int qh = 0; qh < 2; qh++) {
#pragma unroll
                for (int qt = 0; qt < 4; qt++) {
                    const int qw = qh * 64 + qt * 16;      // q window in chunk
                    shortx8 aq = *(const shortx8*)&SA[qw + lm][quad * 8];
                    floatx4 em = emp[qc / 4 + qh * 16 + qt * 4 + quad];
                    shortx4 av0 = *(const shortx4*)&ST[lm][qw + quad * 4];
                    shortx4 av1 = *(const shortx4*)&ST[16 + lm][qw + quad * 4];
#pragma unroll
                    for (int kf = 0; kf < 2; kf++) {
                        floatx4 s = {0.f, 0.f, 0.f, 0.f};
                        s = MFMA32(aq, bkf[kf], s);
                        shortx4 p4;
#pragma unroll
                        for (int r = 0; r < 4; r++) {
                            float e = __builtin_amdgcn_exp2f(s[r] * scale2 + em[r] * LOG2E);
                            psum[kf] += e;
                            p4[r] = f2b(e);
                        }
                        oacc[kf][0] = MFMA16(av0, p4, oacc[kf][0]);
                        oacc[kf][1] = MFMA16(av1, p4, oacc[kf][1]);
                    }
                }
            }
            __syncthreads();
        }
#pragma unroll
        for (int kf = 0; kf < 2; kf++) {
            psum[kf] += __shfl_xor(psum[kf], 16, 64);
            psum[kf] += __shfl_xor(psum[kf], 32, 64);
            float inv = 1.0f / psum[kf];
            int k = khb * 256 + w * 32 + kf * 16 + lm;
            short* op = vctx + ((size_t)(b * 512 + k)) * 256 + h * 32;
#pragma unroll
            for (int di = 0; di < 2; di++) {
                shortx4 o;
#pragma unroll
                for (int r = 0; r < 4; r++) o[r] = f2b(oacc[kf][di][r] * inv);
                *(long long*)(op + di * 16 + quad * 4) = *(long long*)&o;
            }
        }
    }
}

// == PHASE 4a: tail GEMMs, 128x128 tiles, f32 out, global_load_lds staging =====
__global__ __launch_bounds__(256) void phase4a_gemm(
    const short* __restrict__ qctx, const short* __restrict__ vctx,
    const short* __restrict__ val_pad, const short* __restrict__ WTo,
    const short* __restrict__ WT1, const short* __restrict__ WT2,
    float* __restrict__ obuf, float* __restrict__ tbuf) {
    __shared__ short As[128 * 32];
    __shared__ short Bs[128 * 32];
    const int tid = threadIdx.x;
    const int id = blockIdx.x;
    const bool is_out = id < 128;
    int t = is_out ? id : id - 128;
    const int mt = t >> 1, nt = t & 1;
    const int w = tid >> 6, lane = tid & 63;
    const int R0 = (w >> 1) * 64, C0 = (w & 1) * 64;
    const int lm = lane & 15, quad = lane >> 4;
    const int srow = lane >> 2, scol = (lane & 3) * 8;
    const int npair = is_out ? 1 : 2;

    floatx4 acc[4][4];
#pragma unroll
    for (int i = 0; i < 4; i++)
#pragma unroll
        for (int j = 0; j < 4; j++) acc[i][j] = {0.f, 0.f, 0.f, 0.f};

    for (int pair = 0; pair < npair; pair++) {
        const short* Ap = is_out ? (qctx + (size_t)(mt * 128) * 256)
                                 : (pair == 0 ? vctx + (size_t)(mt * 128) * 256
                                              : val_pad + (size_t)(mt * 128) * 256);
        const short* Bp = is_out ? (WTo + (size_t)(nt * 128) * 256)
                                 : (pair == 0 ? WT1 + (size_t)(nt * 128) * 256
                                              : WT2 + (size_t)(nt * 128) * 256);
        for (int kc = 0; kc < 256; kc += 32) {
#pragma unroll
            for (int c = 0; c < 2; c++) {
                const int row = w * 32 + c * 16;
                GLD16(Ap + (size_t)(row + srow) * 256 + kc + scol, &As[row * 32]);
                GLD16(Bp + (size_t)(row + srow) * 256 + kc + scol, &Bs[row * 32]);
            }
            __syncthreads();
            shortx8 af[4], bf[4];
#pragma unroll
            for (int i = 0; i < 4; i++) {
                af[i] = *(const shortx8*)&As[(R0 + i * 16 + lm) * 32 + quad * 8];
                bf[i] = *(const shortx8*)&Bs[(C0 + i * 16 + lm) * 32 + quad * 8];
            }
#pragma unroll
            for (int i = 0; i < 4; i++)
#pragma unroll
                for (int j = 0; j < 4; j++)
                    acc[i][j] = MFMA32(af[i], bf[j], acc[i][j]);
            __syncthreads();
        }
    }
    float* C = is_out ? obuf : tbuf;
    const size_t cbase = (size_t)(mt * 128) * 256 + nt * 128;
#pragma unroll
    for (int i = 0; i < 4; i++) {
#pragma unroll
        for (int j = 0; j < 4; j++) {
            int gn = C0 + j * 16 + lm;
#pragma unroll
            for (int r = 0; r < 4; r++) {
                int gm = R0 + i * 16 + quad * 4 + r;
                C[cbase + (size_t)gm * 256 + gn] = acc[i][j][r];
            }
        }
    }
}

// ===== PHASE 4b: LN epilogues (1 row / wave); gate writes y in-place into tbuf
//       and pushes its row onto a per-dst lock-free list (1 atomicExch / row) ====
__global__ __launch_bounds__(256) void phase4b_ln(
    const float* __restrict__ obuf, const float* __restrict__ bo,
    const float* __restrict__ query, const float* __restrict__ g1,
    const float* __restrict__ be1, float* __restrict__ out_q,
    float* __restrict__ tbuf, const short* __restrict__ vctx,
    const short* __restrict__ val_pad, const float* __restrict__ b1_,
    const float* __restrict__ b2_, const float* __restrict__ g2,
    const float* __restrict__ be2, const float* __restrict__ pad_mask,
    const int* __restrict__ row2e, const int* __restrict__ dst,
    int* __restrict__ head, int* __restrict__ nxt) {
    const int lane = threadIdx.x & 63, w = threadIdx.x >> 6;
    const int c0 = lane * 4;
    if (blockIdx.x < 2048) {
        int row = blockIdx.x * 4 + w;
        long long base = (long long)row * H_ + c0;
        float4 o = *(const float4*)(obuf + base);
        float4 bo4 = *(const float4*)(bo + c0);
        float4 q4 = *(const float4*)(query + base);
        float x0 = o.x + bo4.x + q4.x, x1 = o.y + bo4.y + q4.y;
        float x2 = o.z + bo4.z + q4.z, x3 = o.w + bo4.w + q4.w;
        float t = x0 + x1 + x2 + x3;
        for (int off = 32; off > 0; off >>= 1) t += __shfl_xor(t, off, 64);
        float mean = t * (1.0f / H_);
        float d0 = x0 - mean, d1 = x1 - mean, d2 = x2 - mean, d3 = x3 - mean;
        float v = d0 * d0 + d1 * d1 + d2 * d2 + d3 * d3;
        for (int off = 32; off > 0; off >>= 1) v += __shfl_xor(v, off, 64);
        float rs = rsqrtf(v * (1.0f / H_) + 1e-12f);
        float4 g = *(const float4*)(g1 + c0);
        float4 be = *(const float4*)(be1 + c0);
        float4 out;
        out.x = d0 * rs * g.x + be.x; out.y = d1 * rs * g.y + be.y;
        out.z = d2 * rs * g.z + be.z; out.w = d3 * rs * g.w + be.w;
        *(float4*)(out_q + base) = out;
    } else {
        int row = (blockIdx.x - 2048) * 4 + w;
        if (pad_mask[row] > 0.5f) {
            long long base = (long long)row * H_ + c0;
            float4 tb = *(const float4*)(tbuf + base);
            float4 b14 = *(const float4*)(b1_ + c0);
            float4 b24 = *(const float4*)(b2_ + c0);
            shortx4 vc = *(const shortx4*)(vctx + base);
            shortx4 vp = *(const shortx4*)(val_pad + base);
            float x[4];
#pragma unroll
            for (int j = 0; j < 4; j++) {
                float tv = (j == 0) ? tb.x : (j == 1) ? tb.y : (j == 2) ? tb.z : tb.w;
                float bb1 = (j == 0) ? b14.x : (j == 1) ? b14.y : (j == 2) ? b14.z : b14.w;
                float bb2 = (j == 0) ? b24.x : (j == 1) ? b24.y : (j == 2) ? b24.z : b24.w;
                float th = 1.0f / (1.0f + __expf(-(tv + bb1 + bb2)));
                x[j] = th * b2f(vc[j]) + (1.0f - th) * b2f(vp[j]);
            }
            float t = x[0] + x[1] + x[2] + x[3];
            for (int off = 32; off > 0; off >>= 1) t += __shfl_xor(t, off, 64);
            float mean = t * (1.0f / H_);
            float d0 = x[0] - mean, d1 = x[1] - mean, d2 = x[2] - mean, d3 = x[3] - mean;
            float v = d0 * d0 + d1 * d1 + d2 * d2 + d3 * d3;
            for (int off = 32; off > 0; off >>= 1) v += __shfl_xor(v, off, 64);
            float rs = rsqrtf(v * (1.0f / H_) + 1e-12f);
            float4 g = *(const float4*)(g2 + c0);
            float4 be = *(const float4*)(be2 + c0);
            float4 y4;
            y4.x = d0 * rs * g.x + be.x; y4.y = d1 * rs * g.y + be.y;
            y4.z = d2 * rs * g.z + be.z; y4.w = d3 * rs * g.w + be.w;
            *(float4*)(tbuf + base) = y4;   // in-place: same addresses just read
            if (lane == 0) {
                int d = dst[row2e[row]];
                int prev = atomicExch(&head[d], row);
                nxt[row] = prev;
            }
        }
    }
}

// ================= PHASE 5: finalize (walk per-node edge list) =================
__global__ __launch_bounds__(256) void finalize_graph(
    const int* __restrict__ head, const int* __restrict__ nxt,
    const float* __restrict__ yrows, const float* __restrict__ graph,
    float* __restrict__ out_g) {
    int n = blockIdx.x, c = threadIdx.x;
    long long idx = (long long)n * H_ + c;
    int e = head[n];
    if (e < 0) { out_g[idx] = graph[idx]; return; }
    float acc = 0.f;
    int cnt = 0;
    while (e >= 0) {
        acc += yrows[(size_t)e * H_ + c];
        cnt++;
        e = nxt[e];
    }
    out_g[idx] = acc / (float)cnt;
}

extern "C" void kernel_launch(void* const* d_in, const int* in_sizes, int n_in,
                              void* d_out, int out_size, void* d_ws, size_t ws_size,
                              hipStream_t stream) {
    const float* ext_mask = (const float*)d_in[0];
    const float* query    = (const float*)d_in[1];
    const float* rel      = (const float*)d_in[2];
    const float* graph    = (const float*)d_in[3];
    const int*  src      = (const int*)d_in[4];
    const int*  dst      = (const int*)d_in[5];
    const int*  eb       = (const int*)d_in[6];
    const int*  ep       = (const int*)d_in[7];
    const float* pad_mask = (const float*)d_in[8];
    const float* Wq = (const float*)d_in[9];  const float* bq = (const float*)d_in[10];
    const float* Wk = (const float*)d_in[11]; const float* bk = (const float*)d_in[12];
    const float* Wv = (const float*)d_in[13]; const float* bv = (const float*)d_in[14];
    const float* Wo = (const float*)d_in[15]; const float* bo = (const float*)d_in[16];
    const float* g1 = (const float*)d_in[17]; const float* be1 = (const float*)d_in[18];
    const float* W1 = (const float*)d_in[19]; const float* b1 = (const float*)d_in[20];
    const float* W2 = (const float*)d_in[21]; const float* b2 = (const float*)d_in[22];
    const float* g2 = (const float*)d_in[23]; const float* be2 = (const float*)d_in[24];
    const int E = in_sizes[2] / H_;

    float* out_g = (float*)d_out;
    float* out_q = (float*)d_out + (size_t)N_ * H_;

    short* sp = (short*)d_ws;
    short* key_pad = sp; sp += (size_t)B_ * LK_ * 2 * H_;
    short* val_pad = sp; sp += (size_t)B_ * LK_ * H_;
    short* Qb      = sp; sp += (size_t)B_ * LQ_ * H_;
    short* Kb      = sp; sp += (size_t)B_ * LK_ * H_;
    short* Vt      = sp; sp += (size_t)B_ * H_ * LK_;   // [b][c][k]
    short* Qt      = sp; sp += (size_t)B_ * H_ * LQ_;   // [b][c][q]
    short* qctx    = sp; sp += (size_t)B_ * LQ_ * H_;
    short* vctx    = sp; sp += (size_t)B_ * LK_ * H_;
    short* qbf     = sp; sp += (size_t)B_ * LQ_ * H_;   // query in bf16
    short* WT      = sp; sp += 458752;
    short* WTo = WT + 262144;
    short* WT1 = WT + 327680;
    short* WT2 = WT + 393216;
    int* ip = (int*)(((size_t)sp + 15) & ~(size_t)15);
    int* head  = ip; ip += N_;          // 8192
    int* nxt   = ip; ip += B_ * LK_;    // 16384
    int* row2e = ip; ip += B_ * LK_;    // 16384
    int* ebase = ip; ip += 32;          // per-batch edge base
    float* fp = (float*)(((size_t)ip + 15) & ~(size_t)15);
    float* obuf = fp; fp += (size_t)B_ * LQ_ * H_;   // f32 [8192,256]
    float* tbuf = fp; fp += (size_t)B_ * LK_ * H_;   // f32 [16384,256]

    phase0<<<1, 64, 0, stream>>>(eb, ebase, E);
    phase1<<<8592, 256, 0, stream>>>(graph, rel, src, dst, eb, ep, pad_mask,
                                     query, Wq, Wk, Wv, Wo, W1, W2,
                                     WT, key_pad, val_pad, qbf, head, row2e,
                                     ebase, E);
    phase2_gemm<<<768, 256, 0, stream>>>(qbf, key_pad, val_pad, WT,
                                         bq, bk, bv, Qb, Kb, Vt, Qt);
    phase3_attn<<<768, 512, 0, stream>>>(Qb, Kb, Vt, Qt, pad_mask, ext_mask,
                                         qctx, vctx);
    phase4a_gemm<<<384, 256, 0, stream>>>(qctx, vctx, val_pad, WTo, WT1, WT2,
                                          obuf, tbuf);
    phase4b_ln<<<6144, 256, 0, stream>>>(obuf, bo, query, g1, be1, out_q,
                                         tbuf, vctx, val_pad, b1, b2, g2, be2,
                                         pad_mask, row2e, dst, head, nxt);
    finalize_graph<<<N_, 256, 0, stream>>>(head, nxt, tbuf, graph, out_g);
}

// Round 11
// 229.878 us; speedup vs baseline: 1.0376x; 1.0043x over previous
//
#include <hip/hip_runtime.h>
#include <hip/hip_bf16.h>
#include <string.h>

#define B_ 32
#define LQ_ 256
#define H_ 256
#define NH_ 8
#define LK_ 512
#define N_ 8192
#define DH_ 32

typedef float floatx4 __attribute__((ext_vector_type(4)));
typedef short shortx8 __attribute__((ext_vector_type(8)));
typedef short shortx4 __attribute__((ext_vector_type(4)));

__device__ __forceinline__ short f2b(float f) {
    __hip_bfloat16 h = __float2bfloat16(f);
    short s;
    __builtin_memcpy(&s, &h, 2);
    return s;
}
__device__ __forceinline__ float b2f(short s) {
    unsigned u = ((unsigned)(unsigned short)s) << 16;
    float f;
    __builtin_memcpy(&f, &u, 4);
    return f;
}

#define LOG2E 1.44269504088896f
#define MFMA32(a, b, c) __builtin_amdgcn_mfma_f32_16x16x32_bf16(a, b, c, 0, 0, 0)
#define MFMA16(a, b, c) __builtin_amdgcn_mfma_f32_16x16x16bf16_1k(a, b, c, 0, 0, 0)
// async global->LDS, 16B/lane; LDS dest = wave-uniform base + lane*16 (m97)
typedef const __attribute__((address_space(1))) void* gptr_t;
typedef __attribute__((address_space(3))) void* lptr_t;
#define GLD16(g, l) __builtin_amdgcn_global_load_lds((gptr_t)(g), (lptr_t)(l), 16, 0, 0)

// ====== PHASE 0: per-batch edge-base lower bounds (kills gather's dep chain) ===
__global__ __launch_bounds__(64) void phase0(
    const int* __restrict__ eb, int* __restrict__ ebase, int E) {
    int b = threadIdx.x;
    if (b < 32) {
        int lo = 0, hi = E;
        while (lo < hi) { int mid = (lo + hi) >> 1; if (eb[mid] < b) lo = mid + 1; else hi = mid; }
        ebase[b] = lo;
    }
}

// == PHASE 1: gather (1 row/wave, vector stores) ∥ W-transpose ∥ misc ==========
__global__ __launch_bounds__(256) void phase1(
    const float* __restrict__ graph, const float* __restrict__ rel,
    const int* __restrict__ src, const int* __restrict__ dst,
    const int* __restrict__ eb, const int* __restrict__ ep,
    const float* __restrict__ pad_mask, const float* __restrict__ query,
    const float* __restrict__ Wq, const float* __restrict__ Wk,
    const float* __restrict__ Wv, const float* __restrict__ Wo,
    const float* __restrict__ W1, const float* __restrict__ W2,
    short* __restrict__ WT, short* __restrict__ key_pad,
    short* __restrict__ val_pad, short* __restrict__ qbf,
    int* __restrict__ head, int* __restrict__ row2e,
    const int* __restrict__ ebase, int E) {
    __shared__ short SL[64][72];
    const int bid = blockIdx.x, tid = threadIdx.x;
    if (bid < 4096) {
        // 4 rows / block, 1 row / 64-lane wave; 8 key-cols + 4 val-cols / thread
        int row = bid * 4 + (tid >> 6);
        int t = tid & 63;
        int b = row >> 9, p = row & 511;
        bool valid = pad_mask[row] > 0.5f;
        size_t krow = (size_t)row * 512;
        size_t vrow = (size_t)row * 256;
        int kc = t * 8, vc = t * 4;
        if (valid) {
            int e = ebase[b] + p;
            int s = src[e], d = dst[e];          // wave-uniform -> scalar loads
            const float* sp = (kc < 256) ? (graph + (size_t)s * 256 + kc)
                                         : (rel + (size_t)e * 256 + (kc - 256));
            float4 k1 = *(const float4*)sp;
            float4 k2 = *(const float4*)(sp + 4);
            float4 v4 = *(const float4*)(graph + (size_t)d * 256 + vc);
            shortx8 ko;
            ko[0] = f2b(k1.x); ko[1] = f2b(k1.y); ko[2] = f2b(k1.z); ko[3] = f2b(k1.w);
            ko[4] = f2b(k2.x); ko[5] = f2b(k2.y); ko[6] = f2b(k2.z); ko[7] = f2b(k2.w);
            *(shortx8*)&key_pad[krow + kc] = ko;
            shortx4 vo;
            vo[0] = f2b(v4.x); vo[1] = f2b(v4.y); vo[2] = f2b(v4.z); vo[3] = f2b(v4.w);
            *(long long*)&val_pad[vrow + vc] = *(long long*)&vo;
        } else {
            shortx8 z = {0, 0, 0, 0, 0, 0, 0, 0};
            *(shortx8*)&key_pad[krow + kc] = z;
            *(long long*)&val_pad[vrow + vc] = 0;
        }
    } else if (bid < 4208) {
        // 112 x 64x64 LDS-tiled transposes: WT[woff + n*K + k] = bf16(s[k*256+n])
        int t = bid - 4096;
        const float* s; int K, woff, tt;
        if (t < 16) { s = Wq; K = 256; woff = 0; tt = t; }
        else if (t < 48) { s = Wk; K = 512; woff = 65536; tt = t - 16; }
        else {
            int m = (t - 48) >> 4; tt = (t - 48) & 15; K = 256;
            s = (m == 0) ? Wv : (m == 1) ? Wo : (m == 2) ? W1 : W2;
            woff = 196608 + m * 65536;
        }
        int k0 = (tt >> 2) * 64, n0 = (tt & 3) * 64;
        int rr = tid >> 2, cc = (tid & 3) * 16;
        const float* sp = s + (size_t)(k0 + rr) * 256 + n0 + cc;
#pragma unroll
        for (int j = 0; j < 16; j += 4) {
            float4 v = *(const float4*)(sp + j);
            SL[rr][cc + j + 0] = f2b(v.x); SL[rr][cc + j + 1] = f2b(v.y);
            SL[rr][cc + j + 2] = f2b(v.z); SL[rr][cc + j + 3] = f2b(v.w);
        }
        __syncthreads();
        int nn = tid >> 2, kk = (tid & 3) * 16;
        shortx8 o0, o1;
#pragma unroll
        for (int j = 0; j < 8; j++) { o0[j] = SL[kk + j][nn]; o1[j] = SL[kk + 8 + j][nn]; }
        short* wp = WT + (size_t)woff + (size_t)(n0 + nn) * K + k0 + kk;
        *(shortx8*)wp = o0;
        *(shortx8*)(wp + 8) = o1;
    } else if (bid < 4240) {
        int i = (bid - 4208) * 256 + tid;   // 32 blocks -> 8192 threads
        if (i < 8192) head[i] = -1;
        for (int j = i; j < E; j += 8192)
            row2e[eb[j] * 512 + ep[j]] = j;
    } else {
        // query f32 -> bf16 (numerically identical to in-staging f2b)
        int i = (bid - 4240) * 256 + tid;   // 65536 threads x 32 elems
        const float* qp = query + (size_t)i * 32;
        short* op = qbf + (size_t)i * 32;
#pragma unroll
        for (int j = 0; j < 32; j += 4) {
            float4 v = *(const float4*)(qp + j);
            shortx4 o;
            o[0] = f2b(v.x); o[1] = f2b(v.y); o[2] = f2b(v.z); o[3] = f2b(v.w);
            *(long long*)(op + j) = *(long long*)&o;
        }
    }
}

// ===== PHASE 2: QKV GEMMs, 128x128 tiles, global_load_lds staging (m97-style) ==
__global__ __launch_bounds__(256) void phase2_gemm(
    const short* __restrict__ qbf, const short* __restrict__ key_pad,
    const short* __restrict__ val_pad, const short* __restrict__ WT,
    const float* __restrict__ bq, const float* __restrict__ bk,
    const float* __restrict__ bv,
    short* __restrict__ Qb, short* __restrict__ Kb,
    short* __restrict__ Vt, short* __restrict__ Qt) {
    __shared__ short As[128 * 32];   // unpadded (gload_lds requires linear dest)
    __shared__ short Bs[128 * 32];
    const int tid = threadIdx.x;
    const int id = blockIdx.x;
    const short* Ab; const short* Bb;
    const float* bias; short* C;
    size_t cbase; int cstride, K; bool biasM;
    if (id < 128) {
        int mt = id >> 1, nt = id & 1;
        Ab = qbf + (size_t)(mt * 128) * 256; K = 256;
        Bb = WT + (size_t)(nt * 128) * 256;
        bias = bq + nt * 128; biasM = false;
        C = Qb; cbase = (size_t)(mt * 128) * 256 + nt * 128; cstride = 256;
    } else if (id < 384) {
        int t = id - 128; int mt = t >> 1, nt = t & 1;
        Ab = key_pad + (size_t)(mt * 128) * 512; K = 512;
        Bb = WT + 65536 + (size_t)(nt * 128) * 512;
        bias = bk + nt * 128; biasM = false;
        C = Kb; cbase = (size_t)(mt * 128) * 256 + nt * 128; cstride = 256;
    } else if (id < 640) {
        int t = id - 384; int b = t >> 3, ct = (t >> 2) & 1, nt = t & 3;
        Ab = WT + 196608 + (size_t)(ct * 128) * 256; K = 256;
        Bb = val_pad + ((size_t)(b * 512 + nt * 128)) * 256;
        bias = bv + ct * 128; biasM = true;
        C = Vt; cbase = ((size_t)(b * 256 + ct * 128)) * 512 + nt * 128; cstride = 512;
    } else {
        int t = id - 640; int b = t >> 2, ct = (t >> 1) & 1, qt = t & 1;
        Ab = WT + (size_t)(ct * 128) * 256; K = 256;
        Bb = qbf + ((size_t)(b * 256 + qt * 128)) * 256;
        bias = bq + ct * 128; biasM = true;
        C = Qt; cbase = ((size_t)(b * 256 + ct * 128)) * 256 + qt * 128; cstride = 256;
    }
    const int w = tid >> 6, lane = tid & 63;
    const int R0 = (w >> 1) * 64, C0 = (w & 1) * 64;
    const int lm = lane & 15, quad = lane >> 4;
    const int srow = lane >> 2, scol = (lane & 3) * 8;   // 16 rows x 32 cols / wave-call

    floatx4 acc[4][4];
#pragma unroll
    for (int i = 0; i < 4; i++)
#pragma unroll
        for (int j = 0; j < 4; j++) acc[i][j] = {0.f, 0.f, 0.f, 0.f};

    for (int kc = 0; kc < K; kc += 32) {
#pragma unroll
        for (int c = 0; c < 2; c++) {
            const int row = w * 32 + c * 16;
            GLD16(Ab + (size_t)(row + srow) * K + kc + scol, &As[row * 32]);
            GLD16(Bb + (size_t)(row + srow) * K + kc + scol, &Bs[row * 32]);
        }
        __syncthreads();
        shortx8 af[4], bf[4];
#pragma unroll
        for (int i = 0; i < 4; i++) {
            af[i] = *(const shortx8*)&As[(R0 + i * 16 + lm) * 32 + quad * 8];
            bf[i] = *(const shortx8*)&Bs[(C0 + i * 16 + lm) * 32 + quad * 8];
        }
#pragma unroll
        for (int i = 0; i < 4; i++)
#pragma unroll
            for (int j = 0; j < 4; j++)
                acc[i][j] = MFMA32(af[i], bf[j], acc[i][j]);
        __syncthreads();
    }
#pragma unroll
    for (int i = 0; i < 4; i++) {
#pragma unroll
        for (int j = 0; j < 4; j++) {
            int gn = C0 + j * 16 + lm;
#pragma unroll
            for (int r = 0; r < 4; r++) {
                int gm = R0 + i * 16 + quad * 4 + r;
                float bvv = biasM ? bias[gm] : bias[gn];
                C[cbase + (size_t)gm * cstride + gn] = f2b(acc[i][j][r] + bvv);
            }
        }
    }
}

// ====== PHASE 3: attention, (b,h)-blocked; register-direct P via K=16 PV MFMA ==
__global__ __launch_bounds__(512, 4) void phase3_attn(
    const short* __restrict__ Qm, const short* __restrict__ Km,
    const short* __restrict__ Vt, const short* __restrict__ Qt,
    const float* __restrict__ pad_mask, const float* __restrict__ ext,
    short* __restrict__ qctx, short* __restrict__ vctx) {
    __shared__ short SA[128][40];    // K chunk [k][d] / Q chunk [q][d]
    __shared__ short ST[32][136];    // Vt slice [d][k] / Qt slice [d][q]
    const int tid = threadIdx.x;
    const int w = tid >> 6, lane = tid & 63;
    const int lm = lane & 15, quad = lane >> 4;
    const float scale2 = 0.17677669529663687f * LOG2E;
    const int id = blockIdx.x;

    if (id < 256) {
        const int b = id >> 3, h = id & 7;
        shortx8 bqf[2];
        bqf[0] = *(const shortx8*)(Qm + ((size_t)(b * 256 + w * 32 + lm)) * 256 + h * 32 + quad * 8);
        bqf[1] = *(const shortx8*)(Qm + ((size_t)(b * 256 + w * 32 + 16 + lm)) * 256 + h * 32 + quad * 8);
        floatx4 oacc[2][2] = {{{0.f,0.f,0.f,0.f},{0.f,0.f,0.f,0.f}},
                              {{0.f,0.f,0.f,0.f},{0.f,0.f,0.f,0.f}}};
        float psum[2] = {0.f, 0.f};
        const floatx4* pmp = (const floatx4*)(pad_mask + b * 512);
        for (int kc = 0; kc < 512; kc += 128) {
            if (tid < 256) {          // K chunk [128][32]
                int r = tid >> 1, dq = (tid & 1) * 16;
                const short* kp = Km + ((size_t)(b * 512 + kc + r)) * 256 + h * 32 + dq;
                *(shortx8*)&SA[r][dq] = *(const shortx8*)kp;
                *(shortx8*)&SA[r][dq + 8] = *(const shortx8*)(kp + 8);
            } else {                  // Vt slice [32][128]
                int u = tid - 256;
                int r = u >> 3, kq = (u & 7) * 16;
                const short* vp = Vt + ((size_t)(b * 256 + h * 32 + r)) * 512 + kc + kq;
                *(shortx8*)&ST[r][kq] = *(const shortx8*)vp;
                *(shortx8*)&ST[r][kq + 8] = *(const shortx8*)(vp + 8);
            }
            __syncthreads();
#pragma unroll
            for (int kh = 0; kh < 2; kh++) {
#pragma unroll
                for (int kt = 0; kt < 4; kt++) {
                    const int kw = kh * 64 + kt * 16;      // k window in chunk
                    shortx8 ak = *(const shortx8*)&SA[kw + lm][quad * 8];
                    floatx4 pm = pmp[kc / 4 + kh * 16 + kt * 4 + quad];
                    shortx4 av0 = *(const shortx4*)&ST[lm][kw + quad * 4];
                    shortx4 av1 = *(const shortx4*)&ST[16 + lm][kw + quad * 4];
#pragma unroll
                    for (int qf = 0; qf < 2; qf++) {
                        floatx4 s = {0.f, 0.f, 0.f, 0.f};
                        s = MFMA32(ak, bqf[qf], s);
                        shortx4 p4;
#pragma unroll
                        for (int r = 0; r < 4; r++) {
                            float e = __builtin_amdgcn_exp2f(
                                s[r] * scale2 + (1.0f - pm[r]) * (-10000.0f * LOG2E));
                            psum[qf] += e;
                            p4[r] = f2b(e);
                        }
                        oacc[qf][0] = MFMA16(av0, p4, oacc[qf][0]);
                        oacc[qf][1] = MFMA16(av1, p4, oacc[qf][1]);
                    }
                }
            }
            __syncthreads();
        }
#pragma unroll
        for (int qf = 0; qf < 2; qf++) {
            psum[qf] += __shfl_xor(psum[qf], 16, 64);
            psum[qf] += __shfl_xor(psum[qf], 32, 64);
            float inv = 1.0f / psum[qf];
            int q = w * 32 + qf * 16 + lm;
            short* op = qctx + ((size_t)(b * 256 + q)) * 256 + h * 32;
#pragma unroll
            for (int di = 0; di < 2; di++) {
                shortx4 o;
#pragma unroll
                for (int r = 0; r < 4; r++) o[r] = f2b(oacc[qf][di][r] * inv);
                *(long long*)(op + di * 16 + quad * 4) = *(long long*)&o;
            }
        }
    } else {
        const int t = id - 256;
        const int b = t >> 4, h = (t >> 1) & 7, khb = t & 1;
        shortx8 bkf[2];
        bkf[0] = *(const shortx8*)(Km + ((size_t)(b * 512 + khb * 256 + w * 32 + lm)) * 256 + h * 32 + quad * 8);
        bkf[1] = *(const shortx8*)(Km + ((size_t)(b * 512 + khb * 256 + w * 32 + 16 + lm)) * 256 + h * 32 + quad * 8);
        floatx4 oacc[2][2] = {{{0.f,0.f,0.f,0.f},{0.f,0.f,0.f,0.f}},
                              {{0.f,0.f,0.f,0.f},{0.f,0.f,0.f,0.f}}};
        float psum[2] = {0.f, 0.f};
        const floatx4* emp = (const floatx4*)(ext + b * 256);
        for (int qc = 0; qc < 256; qc += 128) {
            if (tid < 256) {          // Q chunk [128][32]
                int r = tid >> 1, dq = (tid & 1) * 16;
                const short* qp = Qm + ((size_t)(b * 256 + qc + r)) * 256 + h * 32 + dq;
                *(shortx8*)&SA[r][dq] = *(const shortx8*)qp;
                *(shortx8*)&SA[r][dq + 8] = *(const shortx8*)(qp + 8);
            } else {                  // Qt slice [32][128]
                int u = tid - 256;
                int r = u >> 3, kq = (u & 7) * 16;
                const short* tp = Qt + ((size_t)(b * 256 + h * 32 + r)) * 256 + qc + kq;
                *(shortx8*)&ST[r][kq] = *(const shortx8*)tp;
                *(shortx8*)&ST[r][kq + 8] = *(const shortx8*)(tp + 8);
            }
            __syncthreads();
#pragma unroll
            for (int qh = 0; qh < 2; qh++) {
#pragma unroll
                for (int qt = 0; qt < 4; qt++) {
                    const int qw = qh * 64 + qt * 16;      // q window in chunk
                    shortx8 aq = *(const shortx8*)&SA[qw + lm][quad * 8];
                    floatx4 em = emp[qc / 4 + qh * 16 + qt * 4 + quad];
                    shortx4 av0 = *(const shortx4*)&ST[lm][qw + quad * 4];
                    shortx4 av1 = *(const shortx4*)&ST[16 + lm][qw + quad * 4];
#pragma unroll
                    for (int kf = 0; kf < 2; kf++) {
                        floatx4 s = {0.f, 0.f, 0.f, 0.f};
                        s = MFMA32(aq, bkf[kf], s);
                        shortx4 p4;
#pragma unroll
                        for (int r = 0; r < 4; r++) {
                            float e = __builtin_amdgcn_exp2f(s[r] * scale2 + em[r] * LOG2E);
                            psum[kf] += e;
                            p4[r] = f2b(e);
                        }
                        oacc[kf][0] = MFMA16(av0, p4, oacc[kf][0]);
                        oacc[kf][1] = MFMA16(av1, p4, oacc[kf][1]);
                    }
                }
            }
            __syncthreads();
        }
#pragma unroll
        for (int kf = 0; kf < 2; kf++) {
            psum[kf] += __shfl_xor(psum[kf], 16, 64);
            psum[kf] += __shfl_xor(psum[kf], 32, 64);
            float inv = 1.0f / psum[kf];
            int k = khb * 256 + w * 32 + kf * 16 + lm;
            short* op = vctx + ((size_t)(b * 512 + k)) * 256 + h * 32;
#pragma unroll
            for (int di = 0; di < 2; di++) {
                shortx4 o;
#pragma unroll
                for (int r = 0; r < 4; r++) o[r] = f2b(oacc[kf][di][r] * inv);
                *(long long*)(op + di * 16 + quad * 4) = *(long long*)&o;
            }
        }
    }
}

// == PHASE 4a: tail GEMMs, 128x128 tiles, f32 out, global_load_lds staging =====
__global__ __launch_bounds__(256) void phase4a_gemm(
    const short* __restrict__ qctx, const short* __restrict__ vctx,
    const short* __restrict__ val_pad, const short* __restrict__ WTo,
    const short* __restrict__ WT1, const short* __restrict__ WT2,
    float* __restrict__ obuf, float* __restrict__ tbuf) {
    __shared__ short As[128 * 32];
    __shared__ short Bs[128 * 32];
    const int tid = threadIdx.x;
    const int id = blockIdx.x;
    const bool is_out = id < 128;
    int t = is_out ? id : id - 128;
    const int mt = t >> 1, nt = t & 1;
    const int w = tid >> 6, lane = tid & 63;
    const int R0 = (w >> 1) * 64, C0 = (w & 1) * 64;
    const int lm = lane & 15, quad = lane >> 4;
    const int srow = lane >> 2, scol = (lane & 3) * 8;
    const int npair = is_out ? 1 : 2;

    floatx4 acc[4][4];
#pragma unroll
    for (int i = 0; i < 4; i++)
#pragma unroll
        for (int j = 0; j < 4; j++) acc[i][j] = {0.f, 0.f, 0.f, 0.f};

    for (int pair = 0; pair < npair; pair++) {
        const short* Ap = is_out ? (qctx + (size_t)(mt * 128) * 256)
                                 : (pair == 0 ? vctx + (size_t)(mt * 128) * 256
                                              : val_pad + (size_t)(mt * 128) * 256);
        const short* Bp = is_out ? (WTo + (size_t)(nt * 128) * 256)
                                 : (pair == 0 ? WT1 + (size_t)(nt * 128) * 256
                                              : WT2 + (size_t)(nt * 128) * 256);
        for (int kc = 0; kc < 256; kc += 32) {
#pragma unroll
            for (int c = 0; c < 2; c++) {
                const int row = w * 32 + c * 16;
                GLD16(Ap + (size_t)(row + srow) * 256 + kc + scol, &As[row * 32]);
                GLD16(Bp + (size_t)(row + srow) * 256 + kc + scol, &Bs[row * 32]);
            }
            __syncthreads();
            shortx8 af[4], bf[4];
#pragma unroll
            for (int i = 0; i < 4; i++) {
                af[i] = *(const shortx8*)&As[(R0 + i * 16 + lm) * 32 + quad * 8];
                bf[i] = *(const shortx8*)&Bs[(C0 + i * 16 + lm) * 32 + quad * 8];
            }
#pragma unroll
            for (int i = 0; i < 4; i++)
#pragma unroll
                for (int j = 0; j < 4; j++)
                    acc[i][j] = MFMA32(af[i], bf[j], acc[i][j]);
            __syncthreads();
        }
    }
    float* C = is_out ? obuf : tbuf;
    const size_t cbase = (size_t)(mt * 128) * 256 + nt * 128;
#pragma unroll
    for (int i = 0; i < 4; i++) {
#pragma unroll
        for (int j = 0; j < 4; j++) {
            int gn = C0 + j * 16 + lm;
#pragma unroll
            for (int r = 0; r < 4; r++) {
                int gm = R0 + i * 16 + quad * 4 + r;
                C[cbase + (size_t)gm * 256 + gn] = acc[i][j][r];
            }
        }
    }
}

// ===== PHASE 4b: LN epilogues (1 row / wave); gate writes y in-place into tbuf
//       and pushes its row onto a per-dst lock-free list (1 atomicExch / row) ====
__global__ __launch_bounds__(256) void phase4b_ln(
    const float* __restrict__ obuf, const float* __restrict__ bo,
    const float* __restrict__ query, const float* __restrict__ g1,
    const float* __restrict__ be1, float* __restrict__ out_q,
    float* __restrict__ tbuf, const short* __restrict__ vctx,
    const short* __restrict__ val_pad, const float* __restrict__ b1_,
    const float* __restrict__ b2_, const float* __restrict__ g2,
    const float* __restrict__ be2, const float* __restrict__ pad_mask,
    const int* __restrict__ row2e, const int* __restrict__ dst,
    int* __restrict__ head, int* __restrict__ nxt) {
    const int lane = threadIdx.x & 63, w = threadIdx.x >> 6;
    const int c0 = lane * 4;
    if (blockIdx.x < 2048) {
        int row = blockIdx.x * 4 + w;
        long long base = (long long)row * H_ + c0;
        float4 o = *(const float4*)(obuf + base);
        float4 bo4 = *(const float4*)(bo + c0);
        float4 q4 = *(const float4*)(query + base);
        float x0 = o.x + bo4.x + q4.x, x1 = o.y + bo4.y + q4.y;
        float x2 = o.z + bo4.z + q4.z, x3 = o.w + bo4.w + q4.w;
        float t = x0 + x1 + x2 + x3;
        for (int off = 32; off > 0; off >>= 1) t += __shfl_xor(t, off, 64);
        float mean = t * (1.0f / H_);
        float d0 = x0 - mean, d1 = x1 - mean, d2 = x2 - mean, d3 = x3 - mean;
        float v = d0 * d0 + d1 * d1 + d2 * d2 + d3 * d3;
        for (int off = 32; off > 0; off >>= 1) v += __shfl_xor(v, off, 64);
        float rs = rsqrtf(v * (1.0f / H_) + 1e-12f);
        float4 g = *(const float4*)(g1 + c0);
        float4 be = *(const float4*)(be1 + c0);
        float4 out;
        out.x = d0 * rs * g.x + be.x; out.y = d1 * rs * g.y + be.y;
        out.z = d2 * rs * g.z + be.z; out.w = d3 * rs * g.w + be.w;
        *(float4*)(out_q + base) = out;
    } else {
        int row = (blockIdx.x - 2048) * 4 + w;
        if (pad_mask[row] > 0.5f) {
            long long base = (long long)row * H_ + c0;
            float4 tb = *(const float4*)(tbuf + base);
            float4 b14 = *(const float4*)(b1_ + c0);
            float4 b24 = *(const float4*)(b2_ + c0);
            shortx4 vc = *(const shortx4*)(vctx + base);
            shortx4 vp = *(const shortx4*)(val_pad + base);
            float x[4];
#pragma unroll
            for (int j = 0; j < 4; j++) {
                float tv = (j == 0) ? tb.x : (j == 1) ? tb.y : (j == 2) ? tb.z : tb.w;
                float bb1 = (j == 0) ? b14.x : (j == 1) ? b14.y : (j == 2) ? b14.z : b14.w;
                float bb2 = (j == 0) ? b24.x : (j == 1) ? b24.y : (j == 2) ? b24.z : b24.w;
                float th = 1.0f / (1.0f + __expf(-(tv + bb1 + bb2)));
                x[j] = th * b2f(vc[j]) + (1.0f - th) * b2f(vp[j]);
            }
            float t = x[0] + x[1] + x[2] + x[3];
            for (int off = 32; off > 0; off >>= 1) t += __shfl_xor(t, off, 64);
            float mean = t * (1.0f / H_);
            float d0 = x[0] - mean, d1 = x[1] - mean, d2 = x[2] - mean, d3 = x[3] - mean;
            float v = d0 * d0 + d1 * d1 + d2 * d2 + d3 * d3;
            for (int off = 32; off > 0; off >>= 1) v += __shfl_xor(v, off, 64);
            float rs = rsqrtf(v * (1.0f / H_) + 1e-12f);
            float4 g = *(const float4*)(g2 + c0);
            float4 be = *(const float4*)(be2 + c0);
            float4 y4;
            y4.x = d0 * rs * g.x + be.x; y4.y = d1 * rs * g.y + be.y;
            y4.z = d2 * rs * g.z + be.z; y4.w = d3 * rs * g.w + be.w;
            *(float4*)(tbuf + base) = y4;   // in-place: same addresses just read
            if (lane == 0) {
                int d = dst[row2e[row]];
                int prev = atomicExch(&head[d], row);
                nxt[row] = prev;
            }
        }
    }
}

// ================= PHASE 5: finalize (walk per-node edge list) =================
__global__ __launch_bounds__(256) void finalize_graph(
    const int* __restrict__ head, const int* __restrict__ nxt,
    const float* __restrict__ yrows, const float* __restrict__ graph,
    float* __restrict__ out_g) {
    int n = blockIdx.x, c = threadIdx.x;
    long long idx = (long long)n * H_ + c;
    int e = head[n];
    if (e < 0) { out_g[idx] = graph[idx]; return; }
    float acc = 0.f;
    int cnt = 0;
    while (e >= 0) {
        acc += yrows[(size_t)e * H_ + c];
        cnt++;
        e = nxt[e];
    }
    out_g[idx] = acc / (float)cnt;
}

extern "C" void kernel_launch(void* const* d_in, const int* in_sizes, int n_in,
                              void* d_out, int out_size, void* d_ws, size_t ws_size,
                              hipStream_t stream) {
    const float* ext_mask = (const float*)d_in[0];
    const float* query    = (const float*)d_in[1];
    const float* rel      = (const float*)d_in[2];
    const float* graph    = (const float*)d_in[3];
    const int*  src      = (const int*)d_in[4];
    const int*  dst      = (const int*)d_in[5];
    const int*  eb       = (const int*)d_in[6];
    const int*  ep       = (const int*)d_in[7];
    const float* pad_mask = (const float*)d_in[8];
    const float* Wq = (const float*)d_in[9];  const float* bq = (const float*)d_in[10];
    const float* Wk = (const float*)d_in[11]; const float* bk = (const float*)d_in[12];
    const float* Wv = (const float*)d_in[13]; const float* bv = (const float*)d_in[14];
    const float* Wo = (const float*)d_in[15]; const float* bo = (const float*)d_in[16];
    const float* g1 = (const float*)d_in[17]; const float* be1 = (const float*)d_in[18];
    const float* W1 = (const float*)d_in[19]; const float* b1 = (const float*)d_in[20];
    const float* W2 = (const float*)d_in[21]; const float* b2 = (const float*)d_in[22];
    const float* g2 = (const float*)d_in[23]; const float* be2 = (const float*)d_in[24];
    const int E = in_sizes[2] / H_;

    float* out_g = (float*)d_out;
    float* out_q = (float*)d_out + (size_t)N_ * H_;

    short* sp = (short*)d_ws;
    short* key_pad = sp; sp += (size_t)B_ * LK_ * 2 * H_;
    short* val_pad = sp; sp += (size_t)B_ * LK_ * H_;
    short* Qb      = sp; sp += (size_t)B_ * LQ_ * H_;
    short* Kb      = sp; sp += (size_t)B_ * LK_ * H_;
    short* Vt      = sp; sp += (size_t)B_ * H_ * LK_;   // [b][c][k]
    short* Qt      = sp; sp += (size_t)B_ * H_ * LQ_;   // [b][c][q]
    short* qctx    = sp; sp += (size_t)B_ * LQ_ * H_;
    short* vctx    = sp; sp += (size_t)B_ * LK_ * H_;
    short* qbf     = sp; sp += (size_t)B_ * LQ_ * H_;   // query in bf16
    short* WT      = sp; sp += 458752;
    short* WTo = WT + 262144;
    short* WT1 = WT + 327680;
    short* WT2 = WT + 393216;
    int* ip = (int*)(((size_t)sp + 15) & ~(size_t)15);
    int* head  = ip; ip += N_;          // 8192
    int* nxt   = ip; ip += B_ * LK_;    // 16384
    int* row2e = ip; ip += B_ * LK_;    // 16384
    int* ebase = ip; ip += 32;          // per-batch edge base
    float* fp = (float*)(((size_t)ip + 15) & ~(size_t)15);
    float* obuf = fp; fp += (size_t)B_ * LQ_ * H_;   // f32 [8192,256]
    float* tbuf = fp; fp += (size_t)B_ * LK_ * H_;   // f32 [16384,256]

    phase0<<<1, 64, 0, stream>>>(eb, ebase, E);
    phase1<<<4496, 256, 0, stream>>>(graph, rel, src, dst, eb, ep, pad_mask,
                                     query, Wq, Wk, Wv, Wo, W1, W2,
                                     WT, key_pad, val_pad, qbf, head, row2e,
                                     ebase, E);
    phase2_gemm<<<768, 256, 0, stream>>>(qbf, key_pad, val_pad, WT,
                                         bq, bk, bv, Qb, Kb, Vt, Qt);
    phase3_attn<<<768, 512, 0, stream>>>(Qb, Kb, Vt, Qt, pad_mask, ext_mask,
                                         qctx, vctx);
    phase4a_gemm<<<384, 256, 0, stream>>>(qctx, vctx, val_pad, WTo, WT1, WT2,
                                          obuf, tbuf);
    phase4b_ln<<<6144, 256, 0, stream>>>(obuf, bo, query, g1, be1, out_q,
                                         tbuf, vctx, val_pad, b1, b2, g2, be2,
                                         pad_mask, row2e, dst, head, nxt);
    finalize_graph<<<N_, 256, 0, stream>>>(head, nxt, tbuf, graph, out_g);
}